// Round 1
// baseline (2413.409 us; speedup 1.0000x reference)
//
#include <hip/hip_runtime.h>
#include <math.h>

#define NN 1024
#define BB 8
#define NS_ITERS 20

// ---------------- Frobenius norm reduction: sum(P_u^2) -> sc[0] ----------------
__global__ __launch_bounds__(256) void fro_kernel(const float* __restrict__ pu,
                                                  float* __restrict__ sc) {
    int idx = blockIdx.x * blockDim.x + threadIdx.x;
    const float4* p4 = (const float4*)pu;
    const int n4 = NN * NN / 4;
    float v = 0.f;
    for (int i = idx; i < n4; i += gridDim.x * blockDim.x) {
        float4 t = p4[i];
        v += t.x * t.x + t.y * t.y + t.z * t.z + t.w * t.w;
    }
    #pragma unroll
    for (int off = 32; off > 0; off >>= 1) v += __shfl_down(v, off, 64);
    __shared__ float red[4];
    int lane = threadIdx.x & 63, wid = threadIdx.x >> 6;
    if (lane == 0) red[wid] = v;
    __syncthreads();
    if (threadIdx.x == 0) {
        float t = red[0] + red[1] + red[2] + red[3];
        atomicAdd(sc, t);
    }
}

// sc[0]=sum(P_u^2) -> c = N*sqrt(sc0) = ||N*|P_u|||_F ; sc[1] = N/c ; sc[2] = sqrt(c)
__global__ void finalize_kernel(float* sc) {
    float c = (float)NN * sqrtf(sc[0]);
    sc[1] = (float)NN / c;
    sc[2] = sqrtf(c);
}

// Y0 = |P_u| * (N/c) ; Z0 = I
__global__ __launch_bounds__(256) void init_kernel(const float* __restrict__ pu,
                                                   const float* __restrict__ sc,
                                                   float* __restrict__ Y,
                                                   float* __restrict__ Z) {
    int idx = blockIdx.x * blockDim.x + threadIdx.x;  // over NN*NN/4
    float s = sc[1];
    float4 v = ((const float4*)pu)[idx];
    float4 y;
    y.x = fabsf(v.x) * s; y.y = fabsf(v.y) * s; y.z = fabsf(v.z) * s; y.w = fabsf(v.w) * s;
    ((float4*)Y)[idx] = y;
    int row = idx >> 8;            // NN/4 = 256 float4 per row
    int cb  = (idx & 255) << 2;    // first col of this float4
    float4 z;
    z.x = (row == cb + 0) ? 1.f : 0.f;
    z.y = (row == cb + 1) ? 1.f : 0.f;
    z.z = (row == cb + 2) ? 1.f : 0.f;
    z.w = (row == cb + 3) ? 1.f : 0.f;
    ((float4*)Z)[idx] = z;
}

// ---------------- SGEMM 1024x1024x1024, 64x64 tile, 4x4 microtile ----------------
// EPI 0: C = 3I - A*B      EPI 1: C = 0.5 * A*B
template <int EPI>
__device__ __forceinline__ void gemm_body(const float* __restrict__ A,
                                          const float* __restrict__ Bm,
                                          float* __restrict__ C) {
    __shared__ float As[2][16][64];
    __shared__ float Bs[2][16][64];
    const int t  = threadIdx.x;
    const int tx = t & 15, ty = t >> 4;
    const int row0 = blockIdx.y * 64, col0 = blockIdx.x * 64;
    const int am = t >> 2, ak = (t & 3) << 2;      // A-tile load: row am, k ak..ak+3
    const int bk = t >> 4, bn = (t & 15) << 2;     // B-tile load: k bk, col bn..bn+3

    const float* Ap = A + (row0 + am) * NN + ak;
    const float* Bp = Bm + bk * NN + col0 + bn;

    float acc[4][4] = {{0.f, 0.f, 0.f, 0.f}, {0.f, 0.f, 0.f, 0.f},
                       {0.f, 0.f, 0.f, 0.f}, {0.f, 0.f, 0.f, 0.f}};

    float4 a4 = *(const float4*)Ap;
    float4 b4 = *(const float4*)Bp;
    As[0][ak + 0][am] = a4.x; As[0][ak + 1][am] = a4.y;
    As[0][ak + 2][am] = a4.z; As[0][ak + 3][am] = a4.w;
    *(float4*)&Bs[0][bk][bn] = b4;
    __syncthreads();

    int buf = 0;
    for (int kt = 0; kt < NN / 16; ++kt) {
        float4 apre, bpre;
        const bool more = (kt + 1 < NN / 16);
        if (more) {
            apre = *(const float4*)(Ap + (kt + 1) * 16);
            bpre = *(const float4*)(Bp + (kt + 1) * 16 * NN);
        }
        #pragma unroll
        for (int kk = 0; kk < 16; ++kk) {
            float4 av = *(const float4*)&As[buf][kk][ty << 2];
            float4 bv = *(const float4*)&Bs[buf][kk][tx << 2];
            float a_[4] = {av.x, av.y, av.z, av.w};
            float b_[4] = {bv.x, bv.y, bv.z, bv.w};
            #pragma unroll
            for (int i = 0; i < 4; ++i)
                #pragma unroll
                for (int j = 0; j < 4; ++j)
                    acc[i][j] = fmaf(a_[i], b_[j], acc[i][j]);
        }
        if (more) {
            As[buf ^ 1][ak + 0][am] = apre.x; As[buf ^ 1][ak + 1][am] = apre.y;
            As[buf ^ 1][ak + 2][am] = apre.z; As[buf ^ 1][ak + 3][am] = apre.w;
            *(float4*)&Bs[buf ^ 1][bk][bn] = bpre;
        }
        __syncthreads();
        buf ^= 1;
    }

    float* Cp = C + (size_t)(row0 + (ty << 2)) * NN + col0 + (tx << 2);
    #pragma unroll
    for (int i = 0; i < 4; ++i) {
        float4 o;
        if (EPI == 0) {
            o.x = -acc[i][0]; o.y = -acc[i][1]; o.z = -acc[i][2]; o.w = -acc[i][3];
            int d = (row0 + (ty << 2) + i) - (col0 + (tx << 2));
            if (d == 0) o.x += 3.f;
            else if (d == 1) o.y += 3.f;
            else if (d == 2) o.z += 3.f;
            else if (d == 3) o.w += 3.f;
        } else {
            o.x = 0.5f * acc[i][0]; o.y = 0.5f * acc[i][1];
            o.z = 0.5f * acc[i][2]; o.w = 0.5f * acc[i][3];
        }
        *(float4*)(Cp + (size_t)i * NN) = o;
    }
}

__global__ __launch_bounds__(256) void gemm_neg3i(const float* __restrict__ A,
                                                  const float* __restrict__ B,
                                                  float* __restrict__ C) {
    gemm_body<0>(A, B, C);
}

__global__ __launch_bounds__(256) void gemm_half(const float* __restrict__ A,
                                                 const float* __restrict__ B,
                                                 float* __restrict__ C) {
    gemm_body<1>(A, B, C);
}

__global__ __launch_bounds__(256) void gemm_half_dual(const float* __restrict__ A0,
                                                      const float* __restrict__ B0,
                                                      float* __restrict__ C0,
                                                      const float* __restrict__ A1,
                                                      const float* __restrict__ B1,
                                                      float* __restrict__ C1) {
    const float* A = blockIdx.z ? A1 : A0;
    const float* Bm = blockIdx.z ? B1 : B0;
    float* C = blockIdx.z ? C1 : C0;
    gemm_body<1>(A, Bm, C);
}

// P = sqrt(c) * (Y + Y^T)/2
__global__ __launch_bounds__(256) void sym_kernel(const float* __restrict__ Y,
                                                  const float* __restrict__ sc,
                                                  float* __restrict__ P) {
    __shared__ float tile[32][33];
    int i0 = blockIdx.y * 32, j0 = blockIdx.x * 32;
    int tx = threadIdx.x, ty = threadIdx.y;  // block (32,8)
    #pragma unroll
    for (int r = 0; r < 4; ++r)
        tile[ty + 8 * r][tx] = Y[(size_t)(j0 + ty + 8 * r) * NN + i0 + tx];
    __syncthreads();
    float s = 0.5f * sc[2];
    #pragma unroll
    for (int r = 0; r < 4; ++r) {
        int i = i0 + ty + 8 * r;
        P[(size_t)i * NN + j0 + tx] =
            s * (Y[(size_t)i * NN + j0 + tx] + tile[tx][ty + 8 * r]);
    }
}

// out0[b][n][m] = d_b[n]*d_b[m] + |P_u[n,m]| + 0.01*Q_k[n,m]^2 ; d_b = x[0,:]-x[b,:]
__global__ __launch_bounds__(256) void out0_kernel(const float* __restrict__ x,
                                                   const float* __restrict__ pu,
                                                   const float* __restrict__ qk,
                                                   float* __restrict__ out) {
    int i = blockIdx.x * blockDim.x + threadIdx.x;  // over BB*NN*NN/4
    int rem = i & (NN * NN / 4 - 1);
    int b = i >> 18;               // NN*NN/4 = 262144 = 2^18
    int n = rem >> 8;
    int m4 = (rem & 255) << 2;
    float dn = x[n] - x[b * NN + n];
    float4 x0v = *(const float4*)(x + m4);
    float4 xbv = *(const float4*)(x + b * NN + m4);
    float4 pv = ((const float4*)pu)[rem];
    float4 qv = ((const float4*)qk)[rem];
    float4 o;
    o.x = dn * (x0v.x - xbv.x) + fabsf(pv.x) + 0.01f * qv.x * qv.x;
    o.y = dn * (x0v.y - xbv.y) + fabsf(pv.y) + 0.01f * qv.y * qv.y;
    o.z = dn * (x0v.z - xbv.z) + fabsf(pv.z) + 0.01f * qv.z * qv.z;
    o.w = dn * (x0v.w - xbv.w) + fabsf(pv.w) + 0.01f * qv.w * qv.w;
    ((float4*)out)[i] = o;
}

// out1[0][b][j][i] = x[b][i] + (j<N ? +P[j][i] : -P[j-N][i])
__global__ __launch_bounds__(256) void out1_kernel(const float* __restrict__ x,
                                                   const float* __restrict__ P,
                                                   float* __restrict__ out) {
    int i = blockIdx.x * blockDim.x + threadIdx.x;  // over BB*2N*NN/4
    int bj = i >> 8;           // NN/4 = 256
    int i4 = (i & 255) << 2;
    int b = bj >> 11;          // 2N = 2048
    int j = bj & 2047;
    float s = (j < NN) ? 1.f : -1.f;
    int row = (j < NN) ? j : j - NN;
    float4 pv = *(const float4*)(P + (size_t)row * NN + i4);
    float4 xv = *(const float4*)(x + b * NN + i4);
    float4 o;
    o.x = xv.x + s * pv.x; o.y = xv.y + s * pv.y;
    o.z = xv.z + s * pv.z; o.w = xv.w + s * pv.w;
    ((float4*)out)[i] = o;
}

extern "C" void kernel_launch(void* const* d_in, const int* in_sizes, int n_in,
                              void* d_out, int out_size, void* d_ws, size_t ws_size,
                              hipStream_t stream) {
    const float* x  = (const float*)d_in[0];
    const float* pu = (const float*)d_in[1];
    const float* qk = (const float*)d_in[2];
    float* out = (float*)d_out;
    char* ws = (char*)d_ws;
    const size_t MAT = (size_t)NN * NN * sizeof(float);  // 4 MB
    float* Ya = (float*)(ws + 0 * MAT);
    float* Za = (float*)(ws + 1 * MAT);
    float* Yb = (float*)(ws + 2 * MAT);
    float* Zb = (float*)(ws + 3 * MAT);
    float* T  = (float*)(ws + 4 * MAT);
    float* P  = (float*)(ws + 5 * MAT);
    float* sc = (float*)(ws + 6 * MAT);

    hipMemsetAsync(sc, 0, 16, stream);
    fro_kernel<<<256, 256, 0, stream>>>(pu, sc);
    finalize_kernel<<<1, 1, 0, stream>>>(sc);
    init_kernel<<<NN * NN / 4 / 256, 256, 0, stream>>>(pu, sc, Ya, Za);

    dim3 g(16, 16, 1), g2(16, 16, 2);
    for (int it = 0; it < NS_ITERS; ++it) {
        gemm_neg3i<<<g, 256, 0, stream>>>(Za, Ya, T);  // T = 3I - Z*Y
        if (it + 1 < NS_ITERS) {
            gemm_half_dual<<<g2, 256, 0, stream>>>(Ya, T, Yb, T, Za, Zb);
        } else {
            gemm_half<<<g, 256, 0, stream>>>(Ya, T, Yb);  // Z not needed anymore
        }
        float* tmp;
        tmp = Ya; Ya = Yb; Yb = tmp;
        tmp = Za; Za = Zb; Zb = tmp;
    }

    sym_kernel<<<dim3(32, 32, 1), dim3(32, 8, 1), 0, stream>>>(Ya, sc, P);
    out0_kernel<<<(BB * NN * NN / 4) / 256, 256, 0, stream>>>(x, pu, qk, out);
    out1_kernel<<<(BB * 2 * NN * NN / 4) / 256, 256, 0, stream>>>(
        x, P, out + (size_t)BB * NN * NN);
}